// Round 7
// baseline (154.290 us; speedup 1.0000x reference)
//
#include <hip/hip_runtime.h>
#include <hip/hip_bf16.h>

typedef __attribute__((ext_vector_type(4))) float floatx4;
typedef __attribute__((ext_vector_type(8))) int   intx8;

#define FP8_MAX_F 448.0f
#define SCALE_EPS 1e-7f

// ------ fused pre-pass: blocks 0-1791 absmax(x); blocks 1792-2047 quantize W ------------
__global__ void k_pre(const float* __restrict__ x, unsigned* __restrict__ amax, int n4,
                      const float* __restrict__ w, int* __restrict__ wq, int nw16) {
    if (blockIdx.x < 1792) {
        __shared__ float wmax[4];
        int tid = blockIdx.x * 256 + threadIdx.x;
        int stride = 1792 * 256;
        const float4* x4 = (const float4*)x;
        float m = 0.f;
        for (int i = tid; i < n4; i += stride) {
            float4 v = x4[i];
            m = fmaxf(fmaxf(fabsf(v.x), fabsf(v.y)),
                      fmaxf(m, fmaxf(fabsf(v.z), fabsf(v.w))));
        }
        #pragma unroll
        for (int off = 32; off > 0; off >>= 1) m = fmaxf(m, __shfl_xor(m, off, 64));
        if ((threadIdx.x & 63) == 0) wmax[threadIdx.x >> 6] = m;
        __syncthreads();
        if (threadIdx.x == 0) {
            float t = fmaxf(fmaxf(wmax[0], wmax[1]), fmaxf(wmax[2], wmax[3]));
            atomicMax(amax, __float_as_uint(t));
        }
    } else {
        int tid = (blockIdx.x - 1792) * 256 + threadIdx.x;
        int stride = 256 * 256;
        const float4* x4 = (const float4*)w;
        int4* q4 = (int4*)wq;
        for (int i = tid; i < nw16; i += stride) {
            float4 v0 = x4[4*i], v1 = x4[4*i+1], v2 = x4[4*i+2], v3 = x4[4*i+3];
            int4 o;
            o.x = __builtin_amdgcn_cvt_pk_fp8_f32(v0.x, v0.y, 0, false);
            o.x = __builtin_amdgcn_cvt_pk_fp8_f32(v0.z, v0.w, o.x, true);
            o.y = __builtin_amdgcn_cvt_pk_fp8_f32(v1.x, v1.y, 0, false);
            o.y = __builtin_amdgcn_cvt_pk_fp8_f32(v1.z, v1.w, o.y, true);
            o.z = __builtin_amdgcn_cvt_pk_fp8_f32(v2.x, v2.y, 0, false);
            o.z = __builtin_amdgcn_cvt_pk_fp8_f32(v2.z, v2.w, o.z, true);
            o.w = __builtin_amdgcn_cvt_pk_fp8_f32(v3.x, v3.y, 0, false);
            o.w = __builtin_amdgcn_cvt_pk_fp8_f32(v3.z, v3.w, o.w, true);
            q4[i] = o;
        }
    }
}

// ---------------- x: f32 -> e4m3 bytes (HW RNE), scale = max(absmax/448, eps) -------------
__global__ void k_quant_x(const float* __restrict__ x, int* __restrict__ xq,
                          const unsigned* __restrict__ amax, int n16) {
    float scale = fmaxf(__uint_as_float(*amax) / FP8_MAX_F, SCALE_EPS);
    int tid = blockIdx.x * blockDim.x + threadIdx.x;
    int stride = gridDim.x * blockDim.x;
    const float4* x4 = (const float4*)x;
    int4* q4 = (int4*)xq;
    for (int i = tid; i < n16; i += stride) {
        float4 v0 = x4[4*i], v1 = x4[4*i+1], v2 = x4[4*i+2], v3 = x4[4*i+3];
        int4 o;
        o.x = __builtin_amdgcn_cvt_pk_fp8_f32(v0.x / scale, v0.y / scale, 0, false);
        o.x = __builtin_amdgcn_cvt_pk_fp8_f32(v0.z / scale, v0.w / scale, o.x, true);
        o.y = __builtin_amdgcn_cvt_pk_fp8_f32(v1.x / scale, v1.y / scale, 0, false);
        o.y = __builtin_amdgcn_cvt_pk_fp8_f32(v1.z / scale, v1.w / scale, o.y, true);
        o.z = __builtin_amdgcn_cvt_pk_fp8_f32(v2.x / scale, v2.y / scale, 0, false);
        o.z = __builtin_amdgcn_cvt_pk_fp8_f32(v2.z / scale, v2.w / scale, o.z, true);
        o.w = __builtin_amdgcn_cvt_pk_fp8_f32(v3.x / scale, v3.y / scale, 0, false);
        o.w = __builtin_amdgcn_cvt_pk_fp8_f32(v3.z / scale, v3.w / scale, o.w, true);
        q4[i] = o;
    }
}

// ================= 256x256 8-wave MX-fp8 GEMM: 4-phase, pre-barrier reads, no fences ======
// C[M,N] = ws * (A[M,K]fp8 . B[N,K]fp8^T) + bias.  Slab = 128 fp8-K (one 16x16x128 step).
// m201-shaped phases: each phase issues its ds_reads BEFORE its barrier (LDS queue fills
// pre-barrier, processing overlaps barrier-wait + other waves' MFMA), lgkmcnt(0) after,
// setprio around the MFMA cluster. Counted vmcnt(2) once per slab. NO sched_barrier (m141).
#define BM 256
#define BN 256
#define BKQ 128
#define NT 16   // K / BKQ, K = 2048 fixed

#define GLOAD(src, dst) \
    __builtin_amdgcn_global_load_lds((const __attribute__((address_space(1))) void*)(src), \
                                     (__attribute__((address_space(3))) void*)(dst), 16, 0, 0)
#define BARRIER()    asm volatile("s_barrier" ::: "memory")
#define WAIT_VM(n)   asm volatile("s_waitcnt vmcnt(" #n ")" ::: "memory")
#define WAIT_LGKM()  asm volatile("s_waitcnt lgkmcnt(0)" ::: "memory")

#define LDFRAG(dstv, pL, pH, IMM) {                      \
    int4 lo_ = *(const int4*)((pL) + (IMM));             \
    int4 hi_ = *(const int4*)((pH) + (IMM));             \
    dstv = (intx8){lo_.x, lo_.y, lo_.z, lo_.w, hi_.x, hi_.y, hi_.z, hi_.w}; }

#define MFMA_ROW(m, af)                                                            \
    acc[m][0] = __builtin_amdgcn_mfma_scale_f32_16x16x128_f8f6f4(                  \
        af, b0, acc[m][0], 0, 0, 0, 0x7F7F7F7F, 0, 0x7F7F7F7F);                    \
    acc[m][1] = __builtin_amdgcn_mfma_scale_f32_16x16x128_f8f6f4(                  \
        af, b1, acc[m][1], 0, 0, 0, 0x7F7F7F7F, 0, 0x7F7F7F7F);                    \
    acc[m][2] = __builtin_amdgcn_mfma_scale_f32_16x16x128_f8f6f4(                  \
        af, b2, acc[m][2], 0, 0, 0, 0x7F7F7F7F, 0, 0x7F7F7F7F);                    \
    acc[m][3] = __builtin_amdgcn_mfma_scale_f32_16x16x128_f8f6f4(                  \
        af, b3, acc[m][3], 0, 0, 0, 0x7F7F7F7F, 0, 0x7F7F7F7F);

__global__ __launch_bounds__(512, 2) void k_gemm_mx(
    const unsigned char* __restrict__ A, const unsigned char* __restrict__ B,
    const float* __restrict__ bias, const float* __restrict__ wscale,
    float* __restrict__ C, int M, int N, int K) {
    __shared__ __align__(16) unsigned char lds[131072];   // [buf:2][A 32K | B 32K]

    int nwg = gridDim.x;
    int bid = blockIdx.x;
    bid = (bid & 7) * (nwg >> 3) + (bid >> 3);   // XCD swizzle (nwg % 8 == 0)
    int ntn = N / BN;
    int tm = bid / ntn, tn = bid % ntn;
    int row0 = tm * BM, col0 = tn * BN;

    int tid = (int)threadIdx.x;
    int lane = tid & 63, wid = tid >> 6;
    int wr = wid >> 2, wc = wid & 3;             // 2M x 4N waves; per-wave 128x64
    int fr = lane & 15, g = lane >> 4;

    // ---- staging: lane's global byte offset (i-invariant swizzle) + linear LDS dest
    int srow = tid >> 3;                          // 0..63
    int sc   = (tid & 7) ^ (srow & 7);            // logical chunk col (i*64 == 0 mod 8)
    const int offA0 = (row0 + srow) * K + sc * 16;    // + i*131072 + kt
    const int offB0 = (col0 + srow) * K + sc * 16;
    unsigned char* dstA = lds + tid * 16;             // + i*8192 + buf*65536
    unsigned char* dstB = dstA + 32768;

    // ---- fragment bases: r&7 == fr&7 for all fragment rows -> one swizzle per lane
    int c0 = (2 * g) ^ (fr & 7);
    const int aL = wr * 16384 + fr * 128 + c0 * 16;        // + m*2048
    const int aH = wr * 16384 + fr * 128 + (c0 ^ 1) * 16;
    const int bL = 32768 + wc * 8192 + fr * 128 + c0 * 16; // + n*2048
    const int bH = 32768 + wc * 8192 + fr * 128 + (c0 ^ 1) * 16;

    floatx4 acc[8][4];
    #pragma unroll
    for (int m = 0; m < 8; ++m)
        #pragma unroll
        for (int n = 0; n < 4; ++n) acc[m][n] = (floatx4)(0.f);

    // prologue: stage slab 0 into buf0 (8 loads)
    GLOAD(A + offA0,          dstA);
    GLOAD(A + offA0 + 131072, dstA + 8192);
    GLOAD(A + offA0 + 262144, dstA + 16384);
    GLOAD(A + offA0 + 393216, dstA + 24576);
    GLOAD(B + offB0,          dstB);
    GLOAD(B + offB0 + 131072, dstB + 8192);
    GLOAD(B + offB0 + 262144, dstB + 16384);
    GLOAD(B + offB0 + 393216, dstB + 24576);

    for (int t = 0; t < NT; ++t) {
        const int bufo = (t & 1) << 16;
        const int nbufo = bufo ^ 65536;
        const unsigned char* AbL = lds + bufo + aL;
        const unsigned char* AbH = lds + bufo + aH;
        const unsigned char* BbL = lds + bufo + bL;
        const unsigned char* BbH = lds + bufo + bH;
        unsigned char* dA = dstA + nbufo;
        unsigned char* dB = dstB + nbufo;
        const int kn = ((t + 1) & (NT - 1)) * BKQ;   // wrap keeps schedule uniform

        intx8 b0, b1, b2, b3, a0, a1;

        // ---- phase 0: 2 gloads(t+1) -> counted vmcnt -> validate barrier -> 12 reads
        GLOAD(A + kn + offA0,          dA);
        GLOAD(A + kn + offA0 + 131072, dA + 8192);
        WAIT_VM(2);          // slab t's 8 retired; the 2 just-issued stay in flight
        BARRIER();           // buf t valid for all waves
        LDFRAG(b0, BbL, BbH, 0)
        LDFRAG(b1, BbL, BbH, 2048)
        LDFRAG(b2, BbL, BbH, 4096)
        LDFRAG(b3, BbL, BbH, 6144)
        LDFRAG(a0, AbL, AbH, 0)
        LDFRAG(a1, AbL, AbH, 2048)
        WAIT_LGKM();
        __builtin_amdgcn_s_setprio(1);
        MFMA_ROW(0, a0)
        MFMA_ROW(1, a1)
        __builtin_amdgcn_s_setprio(0);
        BARRIER();

        // ---- phase 1: reads BEFORE barrier (overlap other waves' phase-0 MFMA tail)
        LDFRAG(a0, AbL, AbH, 4096)
        LDFRAG(a1, AbL, AbH, 6144)
        GLOAD(A + kn + offA0 + 262144, dA + 16384);
        GLOAD(A + kn + offA0 + 393216, dA + 24576);
        BARRIER();
        WAIT_LGKM();
        __builtin_amdgcn_s_setprio(1);
        MFMA_ROW(2, a0)
        MFMA_ROW(3, a1)
        __builtin_amdgcn_s_setprio(0);
        BARRIER();

        // ---- phase 2
        LDFRAG(a0, AbL, AbH, 8192)
        LDFRAG(a1, AbL, AbH, 10240)
        GLOAD(B + kn + offB0,          dB);
        GLOAD(B + kn + offB0 + 131072, dB + 8192);
        BARRIER();
        WAIT_LGKM();
        __builtin_amdgcn_s_setprio(1);
        MFMA_ROW(4, a0)
        MFMA_ROW(5, a1)
        __builtin_amdgcn_s_setprio(0);
        BARRIER();

        // ---- phase 3
        LDFRAG(a0, AbL, AbH, 12288)
        LDFRAG(a1, AbL, AbH, 14336)
        GLOAD(B + kn + offB0 + 262144, dB + 16384);
        GLOAD(B + kn + offB0 + 393216, dB + 24576);
        BARRIER();
        WAIT_LGKM();
        __builtin_amdgcn_s_setprio(1);
        MFMA_ROW(6, a0)
        MFMA_ROW(7, a1)
        __builtin_amdgcn_s_setprio(0);
        BARRIER();           // all waves done with buf t before slab t+1 overwrites it
    }

    WAIT_VM(0);   // drain wrap-around staging before exit

    // epilogue: C/D layout (shape-determined): col=lane&15, row=(lane>>4)*4+j
    float wsv = *wscale;
    int crow = (lane >> 4) * 4;
    int ccol = lane & 15;
    float bv[4];
    #pragma unroll
    for (int n = 0; n < 4; ++n) bv[n] = bias[col0 + wc * 64 + n * 16 + ccol];
    #pragma unroll
    for (int m = 0; m < 8; ++m) {
        int r = row0 + wr * 128 + m * 16 + crow;
        #pragma unroll
        for (int n = 0; n < 4; ++n) {
            int c = col0 + wc * 64 + n * 16 + ccol;
            #pragma unroll
            for (int j = 0; j < 4; ++j)
                C[(long)(r + j) * N + c] = acc[m][n][j] * wsv + bv[n];
        }
    }
}

extern "C" void kernel_launch(void* const* d_in, const int* in_sizes, int n_in,
                              void* d_out, int out_size, void* d_ws, size_t ws_size,
                              hipStream_t stream) {
    const float* x      = (const float*)d_in[0];
    const float* w      = (const float*)d_in[1];
    const float* wscale = (const float*)d_in[2];
    const float* bias   = (const float*)d_in[3];
    float* out = (float*)d_out;

    const int K = 2048, N = 2048;
    const int M = in_sizes[0] / K;     // 16384

    unsigned char* ws = (unsigned char*)d_ws;
    unsigned* amax = (unsigned*)ws;                          // 4 B
    int* wq = (int*)(ws + 1024);                             // N*K   = 4.2 MB fp8
    int* xq = (int*)(ws + 1024 + (size_t)N * K);             // M*K   = 33.5 MB fp8

    hipMemsetAsync(amax, 0, 4, stream);
    k_pre<<<2048, 256, 0, stream>>>(x, amax, (M * K) / 4, w, wq, (N * K) / 16);
    k_quant_x<<<2048, 256, 0, stream>>>(x, xq, amax, (M * K) / 16);

    int grid = (M / BM) * (N / BN);    // 64 * 8 = 512
    k_gemm_mx<<<grid, 512, 0, stream>>>((const unsigned char*)xq, (const unsigned char*)wq,
                                        bias, wscale, out, M, N, K);
}